// Round 22
// baseline (72.804 us; speedup 1.0000x reference)
//
#include <hip/hip_runtime.h>
#include <hip/hip_bf16.h>
#include <math.h>

typedef __bf16 bf16;
typedef __bf16 bf16x4 __attribute__((ext_vector_type(4)));
typedef __bf16 bf16x8 __attribute__((ext_vector_type(8)));
typedef float f32x2 __attribute__((ext_vector_type(2)));
typedef float f32x4 __attribute__((ext_vector_type(4)));

#define NB 4
#define NN 1024
#define ND 256
#define NH 8
#define INFV 1e38f
#define RTHR2 11.5f          // defer-max threshold, log2 domain (~e^8)
#define LOG2E 1.44269504f
#define ZSPLIT 4

__device__ __forceinline__ f32x4 mfma16(bf16x8 a, bf16x8 b, f32x4 c) {
    return __builtin_amdgcn_mfma_f32_16x16x32_bf16(a, b, c, 0, 0, 0);
}
__device__ __forceinline__ f32x2 sp2(float v) { return f32x2{v, v}; }
__device__ __forceinline__ f32x2 fma2(f32x2 a, float b, f32x2 c) {
    return __builtin_elementwise_fma(a, sp2(b), c);
}
// force a wave-uniform float into an SGPR
__device__ __forceinline__ float rfl(float x) {
    return __int_as_float(__builtin_amdgcn_readfirstlane(__float_as_int(x)));
}

// one-time: WtG[z][col][k] = (bf16) W_z[k][col]  (32x32 LDS transpose)
__global__ __launch_bounds__(256)
void wtr_k(const float* __restrict__ Wq, const float* __restrict__ Wk,
           const float* __restrict__ Wv, const float* __restrict__ Wo,
           bf16* __restrict__ WtG)
{
    const int z = blockIdx.z;
    const float* W = (z == 0) ? Wq : (z == 1) ? Wk : (z == 2) ? Wv : Wo;
    __shared__ float Ts[32][33];
    const int k0 = blockIdx.x * 32, c0 = blockIdx.y * 32;
    const int tx = threadIdx.x & 31, ty = threadIdx.x >> 5;   // 32 x 8
    #pragma unroll
    for (int i = 0; i < 4; ++i)
        Ts[ty + 8*i][tx] = W[(size_t)(k0 + ty + 8*i)*256 + c0 + tx];
    __syncthreads();
    #pragma unroll
    for (int i = 0; i < 4; ++i)
        WtG[((size_t)z*256 + c0 + ty + 8*i)*256 + k0 + tx] =
            (bf16)Ts[tx][ty + 8*i];
}

// C = A(Mx256) @ W(256x64-tile) + bias. 64x64 tile, 4 waves (2x2), 256 thr.
// W comes pre-transposed + bf16 (WtG[z][col][k]) — 1 coalesced bf16x8 load
// per thread per k-tile (was 8 strided dword loads + 8 cvts).
// MODE0: A is f32; z<2 -> bf16 Go; z==2 -> bf16 Vfb + transposed bf16 Gt.
// MODE1: A and addsrc are bf16 (combined O1); Fo1 = addsrc + relu(C), f32 out.
template<int MODE>
__global__ __launch_bounds__(256)
void gemm_k(const float* __restrict__ A, const bf16* __restrict__ WtG,
            const float* __restrict__ b0, const float* __restrict__ b1,
            const float* __restrict__ b2,
            bf16* __restrict__ Vfb, bf16* __restrict__ G0,
            bf16* __restrict__ G1, bf16* __restrict__ Gt,
            float* __restrict__ Fo1, const bf16* __restrict__ Ab)
{
    const int z = blockIdx.z;
    const bf16* Wt_g  = WtG + (size_t)((MODE == 1) ? 3 : z)*256*256;
    const float* bias = (z == 0) ? b0 : (z == 1) ? b1 : b2;

    const int brow = blockIdx.x * 64;
    const int bcol = blockIdx.y * 64;
    const int t    = threadIdx.x;
    const int lane = t & 63;
    const int w    = t >> 6;
    const int wr   = w >> 1, wc = w & 1;
    const int g    = lane >> 4;
    const int l16  = lane & 15;

    __shared__ bf16 As[64][40];
    __shared__ bf16 Wt[64][40];

    f32x4 acc[2][2];
    #pragma unroll
    for (int i = 0; i < 2; ++i)
        #pragma unroll
        for (int j = 0; j < 2; ++j) acc[i][j] = f32x4{0.f, 0.f, 0.f, 0.f};

    const int ar = t >> 2, aj = (t & 3) * 8;
    const int wcs = t >> 2, wks = (t & 3) * 8;   // W-stage: col, k-octet

    for (int k0 = 0; k0 < 256; k0 += 32) {
        if (MODE == 1) {
            *(bf16x8*)&As[ar][aj] =
                *(const bf16x8*)&Ab[(size_t)(brow + ar)*ND + k0 + aj];
        } else {
            const float4 v0 = *(const float4*)&A[(size_t)(brow + ar)*ND + k0 + aj];
            const float4 v1 = *(const float4*)&A[(size_t)(brow + ar)*ND + k0 + aj + 4];
            bf16x8 w8 = { (bf16)v0.x, (bf16)v0.y, (bf16)v0.z, (bf16)v0.w,
                          (bf16)v1.x, (bf16)v1.y, (bf16)v1.z, (bf16)v1.w };
            *(bf16x8*)&As[ar][aj] = w8;
        }
        *(bf16x8*)&Wt[wcs][wks] =
            *(const bf16x8*)&Wt_g[(size_t)(bcol + wcs)*256 + k0 + wks];
        __syncthreads();

        bf16x8 af[2], bfj[2];
        #pragma unroll
        for (int i = 0; i < 2; ++i) af[i]  = *(const bf16x8*)&As[wr*32 + i*16 + l16][8*g];
        #pragma unroll
        for (int j = 0; j < 2; ++j) bfj[j] = *(const bf16x8*)&Wt[wc*32 + j*16 + l16][8*g];
        #pragma unroll
        for (int j = 0; j < 2; ++j)
            #pragma unroll
            for (int i = 0; i < 2; ++i) acc[i][j] = mfma16(af[i], bfj[j], acc[i][j]);
        __syncthreads();
    }

    #pragma unroll
    for (int j = 0; j < 2; ++j) {
        const int col = bcol + wc*32 + j*16 + l16;
        const float bj = bias[col];
        #pragma unroll
        for (int i = 0; i < 2; ++i) {
            const int row0 = brow + wr*32 + i*16 + 4*g;
            if (MODE == 1) {
                #pragma unroll
                for (int r = 0; r < 4; ++r) {
                    const size_t idx = (size_t)(row0 + r)*ND + col;
                    Fo1[idx] = (float)Ab[idx] + fmaxf(acc[i][j][r] + bj, 0.f);
                }
            } else if (z < 2) {
                bf16* Go = (z == 0) ? G0 : G1;
                #pragma unroll
                for (int r = 0; r < 4; ++r)
                    Go[(size_t)(row0 + r)*ND + col] = (bf16)(acc[i][j][r] + bj);
            } else {
                float vv[4];
                #pragma unroll
                for (int r = 0; r < 4; ++r) {
                    vv[r] = acc[i][j][r] + bj;
                    Vfb[(size_t)(row0 + r)*ND + col] = (bf16)vv[r];
                }
                const int b2i = row0 >> 10;
                const int n0 = row0 & 1023;
                bf16x4 tv = { (bf16)vv[0], (bf16)vv[1], (bf16)vv[2], (bf16)vv[3] };
                *(bf16x4*)&Gt[((size_t)b2i*ND + col)*NN + n0] = tv;
            }
        }
    }
}

// Fused attention — R18/R20/R21 champion structure: 256 thr = 4 waves = 4
// heads (grid.y = batch*2); X_pairs staged cooperatively in LDS (dbuf, b128
// writes); K/V/X/pk register-prefetched one tile ahead; P transposed through
// wave-private LDS; gate weights in SGPRs; log2-domain defer-max softmax;
// ZSPLIT=4; bf16 Ohp partials. UNCHANGED from R21 (best measured).
__global__ __launch_bounds__(256, 4)
void attn_k(const bf16* __restrict__ Qb, const bf16* __restrict__ Kb,
            const bf16* __restrict__ Vt, const float* __restrict__ Xpg,
            const float* __restrict__ prq, const float* __restrict__ prk,
            const float* __restrict__ Wg1, const float* __restrict__ bg1,
            const float* __restrict__ wg2, const float* __restrict__ bg2,
            bf16* __restrict__ Ohp, float* __restrict__ ml)
{
    const int yb   = blockIdx.y;
    const int b    = yb >> 1;
    const int hg   = yb & 1;
    const int q0   = blockIdx.x * 16;
    const int z    = blockIdx.z;
    const int mb0  = z * (NN/ZSPLIT);
    const int t    = threadIdx.x;
    const int w    = t >> 6;        // wave 0..3
    const int h    = hg*4 + w;      // head 0..7
    const int lane = t & 63;
    const int g    = lane >> 4;
    const int l16  = lane & 15;
    const int NT   = NN/ZSPLIT/32;  // 8

    __shared__ float Xps[2][16*132];
    __shared__ bf16  Ps[4][16][40];

    // head gate weights -> SGPRs (wave-uniform); LOG2E folded into 2nd layer
    float g1[3][3], gb1[3], g2v[3], gb2v;
    #pragma unroll
    for (int c = 0; c < 3; ++c)
        #pragma unroll
        for (int d = 0; d < 3; ++d) g1[c][d] = rfl(Wg1[(h*3 + c)*3 + d]);
    #pragma unroll
    for (int d = 0; d < 3; ++d) {
        gb1[d] = rfl(bg1[h*3 + d]);
        g2v[d] = rfl(wg2[h*3 + d]*LOG2E);
    }
    gb2v = rfl(bg2[h]*LOG2E);
    const float sscale = 0.0625f * LOG2E;

    const bf16x8 qf = *(const bf16x8*)&Qb[((size_t)b*NN + q0 + l16)*ND + h*32 + 8*g];

    bool okq[4];
    #pragma unroll
    for (int r = 0; r < 4; ++r)
        okq[r] = prq[b*NN + q0 + 4*g + r] > 0.5f;

    float m_run[4], l_run[4];   // log2-domain max; per-lane partial sum
    f32x4 oh[2];
    #pragma unroll
    for (int r = 0; r < 4; ++r) { m_run[r] = -INFINITY; l_run[r] = 0.f; }
    oh[0] = f32x4{0.f,0.f,0.f,0.f};
    oh[1] = f32x4{0.f,0.f,0.f,0.f};

    const bf16*  kp0 = &Kb[((size_t)b*NN + mb0 + l16)*ND + h*32 + 8*g];
    const bf16*  kp1 = kp0 + (size_t)16*ND;
    const bf16*  vp0 = &Vt[((size_t)b*ND + h*32 + l16)*NN + mb0 + 8*g];
    const bf16*  vp1 = vp0 + (size_t)16*NN;
    const int    xq  = t >> 5, xm = t & 31;   // xq 0..7; stage rows xq and xq+8
    const float* xppA = &Xpg[(((size_t)b*NN + q0 + xq)*NN + mb0 + xm)*3];
    const float* xppB = &Xpg[(((size_t)b*NN + q0 + xq + 8)*NN + mb0 + xm)*3];
    const float* pkp  = &prk[(size_t)b*NN + mb0 + l16];

    // ---- prologue: tile-0 fragments + Xps[0] (b128 stores) ----
    bf16x8 kf0 = *(const bf16x8*)kp0;
    bf16x8 kf1 = *(const bf16x8*)kp1;
    bf16x8 vf0 = *(const bf16x8*)vp0;
    bf16x8 vf1 = *(const bf16x8*)vp1;
    float xxA = xppA[0], xyA = xppA[1], xzA = xppA[2];
    float xxB = xppB[0], xyB = xppB[1], xzB = xppB[2];
    float pk0 = pkp[0], pk1 = pkp[16];
    {
        *(float4*)&Xps[0][xq*132 + xm*4]       = float4{xxA, xyA, xzA, 0.f};
        *(float4*)&Xps[0][(xq + 8)*132 + xm*4] = float4{xxB, xyB, xzB, 0.f};
    }
    __syncthreads();

    for (int it = 0; it < NT; ++it) {
        const int cur = it & 1;

        // issue next-tile loads (consumed next iter)
        bf16x8 kn0, kn1, vn0, vn1;
        float  xnxA, xnyA, xnzA, xnxB, xnyB, xnzB, pn0, pn1;
        if (it + 1 < NT) {
            const int off = (it + 1) * 32;
            kn0 = *(const bf16x8*)(kp0 + (size_t)off*ND);
            kn1 = *(const bf16x8*)(kp1 + (size_t)off*ND);
            vn0 = *(const bf16x8*)(vp0 + off);
            vn1 = *(const bf16x8*)(vp1 + off);
            xnxA = xppA[(size_t)off*3];
            xnyA = xppA[(size_t)off*3 + 1];
            xnzA = xppA[(size_t)off*3 + 2];
            xnxB = xppB[(size_t)off*3];
            xnyB = xppB[(size_t)off*3 + 1];
            xnzB = xppB[(size_t)off*3 + 2];
            pn0 = pkp[off]; pn1 = pkp[off + 16];
        }

        // QK^T
        const f32x4 zero = {0.f,0.f,0.f,0.f};
        f32x4 s[2];
        s[0] = mfma16(qf, kf0, zero);
        s[1] = mfma16(qf, kf1, zero);

        const bool okk0 = pk0 > 0.5f;
        const bool okk1 = pk1 > 0.5f;

        // loc gate (packed f32 over r-pairs) + masks; log2 domain
        float lv[2][4];
        #pragma unroll
        for (int mg = 0; mg < 2; ++mg) {
            const bool okkm = mg ? okk1 : okk0;
            const int m = mg*16 + l16;
            #pragma unroll
            for (int rp = 0; rp < 2; ++rp) {
                const int q = 4*g + 2*rp;
                const float4 xa = *(const float4*)&Xps[cur][q*132 + m*4];
                const float4 xb = *(const float4*)&Xps[cur][(q+1)*132 + m*4];
                const f32x2 vx = {xa.x, xb.x};
                const f32x2 vy = {xa.y, xb.y};
                const f32x2 vz = {xa.z, xb.z};
                f32x2 h0 = fma2(vz, g1[2][0], fma2(vy, g1[1][0], fma2(vx, g1[0][0], sp2(gb1[0]))));
                f32x2 h1 = fma2(vz, g1[2][1], fma2(vy, g1[1][1], fma2(vx, g1[0][1], sp2(gb1[1]))));
                f32x2 h2 = fma2(vz, g1[2][2], fma2(vy, g1[1][2], fma2(vx, g1[0][2], sp2(gb1[2]))));
                const f32x2 zz = {0.f, 0.f};
                h0 = __builtin_elementwise_max(h0, zz);
                h1 = __builtin_elementwise_max(h1, zz);
                h2 = __builtin_elementwise_max(h2, zz);
                f32x2 loc = fma2(h2, g2v[2], fma2(h1, g2v[1], fma2(h0, g2v[0], sp2(gb2v))));
                const f32x2 s2 = { s[mg][2*rp], s[mg][2*rp+1] };
                const f32x2 y = fma2(s2, sscale, loc);
                lv[mg][2*rp]   = (okq[2*rp]   && okkm) ? y.x : -INFV;
                lv[mg][2*rp+1] = (okq[2*rp+1] && okkm) ? y.y : -INFV;
            }
        }

        // defer-max online softmax (log2 domain)
        float pm[4];
        #pragma unroll
        for (int r = 0; r < 4; ++r) pm[r] = fmaxf(lv[0][r], lv[1][r]);
        const bool cond = (pm[0] <= m_run[0] + RTHR2) && (pm[1] <= m_run[1] + RTHR2)
                       && (pm[2] <= m_run[2] + RTHR2) && (pm[3] <= m_run[3] + RTHR2);
        if (!__all((int)cond)) {
            #pragma unroll
            for (int r = 0; r < 4; ++r) {
                float mx = pm[r];
                mx = fmaxf(mx, __shfl_xor(mx, 1));
                mx = fmaxf(mx, __shfl_xor(mx, 2));
                mx = fmaxf(mx, __shfl_xor(mx, 4));
                mx = fmaxf(mx, __shfl_xor(mx, 8));
                const float mnew = fmaxf(m_run[r], mx);
                const float corr = exp2f(m_run[r] - mnew);
                l_run[r] *= corr;
                oh[0][r] *= corr;
                oh[1][r] *= corr;
                m_run[r] = mnew;
            }
        }
        #pragma unroll
        for (int r = 0; r < 4; ++r) {
            const float p0 = exp2f(lv[0][r] - m_run[r]);
            const float p1 = exp2f(lv[1][r] - m_run[r]);
            Ps[w][4*g + r][l16]      = (bf16)p0;
            Ps[w][4*g + r][16 + l16] = (bf16)p1;
            l_run[r] += p0 + p1;
        }

        // PV (compiler orders Ps write->read with a precise lgkmcnt)
        const bf16x8 pf = *(const bf16x8*)&Ps[w][l16][8*g];
        oh[0] = mfma16(pf, vf0, oh[0]);
        oh[1] = mfma16(pf, vf1, oh[1]);

        // stage next X tile into the other buffer (b128); rotate registers
        if (it + 1 < NT) {
            *(float4*)&Xps[cur ^ 1][xq*132 + xm*4]       = float4{xnxA, xnyA, xnzA, 0.f};
            *(float4*)&Xps[cur ^ 1][(xq + 8)*132 + xm*4] = float4{xnxB, xnyB, xnzB, 0.f};
            kf0 = kn0; kf1 = kn1; vf0 = vn0; vf1 = vn1;
            pk0 = pn0; pk1 = pn1;
        }
        __syncthreads();
    }

    // epilogue: unnormalized partial oh (bf16) + (m, l) per row/head
    #pragma unroll
    for (int r = 0; r < 4; ++r) {
        float ls = l_run[r];
        ls += __shfl_xor(ls, 1);
        ls += __shfl_xor(ls, 2);
        ls += __shfl_xor(ls, 4);
        ls += __shfl_xor(ls, 8);
        const int n = q0 + 4*g + r;
        #pragma unroll
        for (int dg = 0; dg < 2; ++dg) {
            const int col = h*32 + dg*16 + l16;
            Ohp[(((size_t)z*NB + b)*NN + n)*ND + col] = (bf16)oh[dg][r];
        }
        if (l16 == 0) {
            const size_t mi = ((((size_t)z*NB + b)*NN + n)*NH + h)*2;
            ml[mi]   = m_run[r];
            ml[mi+1] = ls;
        }
    }
}

// combine ZSPLIT key-quarters: O1 = Vf + (Σ oh_z w_z) / (Σ l_z w_z), bf16 out
__global__ __launch_bounds__(256)
void comb_k(const bf16* __restrict__ Ohp, const float* __restrict__ ml,
            const bf16* __restrict__ Vfb, bf16* __restrict__ O1b)
{
    const int idx = blockIdx.x * 256 + threadIdx.x;
    const int dq = idx & 63;
    const int bn = idx >> 6;
    const int d0 = dq * 4;
    const int h  = dq >> 3;

    const size_t base = ((size_t)bn*NH + h)*2;
    const size_t zstr = (size_t)NB*NN*NH*2;
    float mz[ZSPLIT], lz[ZSPLIT];
    float M = -INFINITY;
    #pragma unroll
    for (int zi = 0; zi < ZSPLIT; ++zi) {
        mz[zi] = ml[base + zi*zstr];
        lz[zi] = ml[base + zi*zstr + 1];
        M = fmaxf(M, mz[zi]);
    }
    float wz[ZSPLIT], den = 0.f;
    #pragma unroll
    for (int zi = 0; zi < ZSPLIT; ++zi) {
        wz[zi] = exp2f(mz[zi] - M);
        den = fmaf(lz[zi], wz[zi], den);
    }
    const float inv = 1.f / den;

    const size_t e = (size_t)bn*ND + d0;
    f32x4 num = {0.f,0.f,0.f,0.f};
    #pragma unroll
    for (int zi = 0; zi < ZSPLIT; ++zi) {
        const bf16x4 o = *(const bf16x4*)&Ohp[e + (size_t)zi*NB*NN*ND];
        #pragma unroll
        for (int r = 0; r < 4; ++r) num[r] = fmaf((float)o[r], wz[zi], num[r]);
    }
    const bf16x4 vf = *(const bf16x4*)&Vfb[e];
    bf16x4 out;
    #pragma unroll
    for (int r = 0; r < 4; ++r) out[r] = (bf16)((float)vf[r] + num[r]*inv);
    *(bf16x4*)&O1b[e] = out;
}

extern "C" void kernel_launch(void* const* d_in, const int* in_sizes, int n_in,
                              void* d_out, int out_size, void* d_ws, size_t ws_size,
                              hipStream_t stream)
{
    const float* Y   = (const float*)d_in[1];
    const float* Xp  = (const float*)d_in[2];
    const float* prq = (const float*)d_in[3];
    const float* prk = (const float*)d_in[4];
    const float* Wq  = (const float*)d_in[5];
    const float* bq  = (const float*)d_in[6];
    const float* Wk  = (const float*)d_in[7];
    const float* bk  = (const float*)d_in[8];
    const float* Wv  = (const float*)d_in[9];
    const float* bv  = (const float*)d_in[10];
    const float* Wo  = (const float*)d_in[11];
    const float* bo  = (const float*)d_in[12];
    const float* Wg1 = (const float*)d_in[13];
    const float* bg1 = (const float*)d_in[14];
    const float* wg2 = (const float*)d_in[15];
    const float* bg2 = (const float*)d_in[16];
    float* out = (float*)d_out;

    const size_t BND = (size_t)NB * NN * ND;   // 1M
    bf16*  Vfb = (bf16*)d_ws;                            // 2 MB
    bf16*  Ohp = Vfb + BND;                              // 8 MB (z=0..3, bf16)
    float* ml  = (float*)(Ohp + (size_t)ZSPLIT*BND);     // 1 MB
    bf16*  Qb  = (bf16*)(ml + (size_t)ZSPLIT*NB*NN*NH*2);// 2 MB
    bf16*  Kb  = Qb + BND;                               // 2 MB
    bf16*  Vt  = Kb + BND;                               // 2 MB
    bf16*  WtG = Vt + BND;                               // 512 KB (4 x 256x256)
    bf16*  O1b = Qb;                                     // aliases Qb (dead after attn)

    wtr_k<<<dim3(8, 8, 4), 256, 0, stream>>>(Wq, Wk, Wv, Wo, WtG);

    gemm_k<0><<<dim3(64, 4, 3), 256, 0, stream>>>(
        Y, WtG, bq, bk, bv,
        Vfb, Qb, Kb, Vt, nullptr, nullptr);

    attn_k<<<dim3(NN/16, NB*2, ZSPLIT), 256, 0, stream>>>(
        Qb, Kb, Vt, Xp, prq, prk, Wg1, bg1, wg2, bg2, Ohp, ml);

    comb_k<<<dim3(1024), 256, 0, stream>>>(Ohp, ml, Vfb, O1b);

    gemm_k<1><<<dim3(64, 4, 1), 256, 0, stream>>>(
        nullptr, WtG, bo, bo, bo,
        nullptr, nullptr, nullptr, nullptr, out, O1b);
}

// Round 23
// 67.964 us; speedup vs baseline: 1.0712x; 1.0712x over previous
//
#include <hip/hip_runtime.h>
#include <hip/hip_bf16.h>
#include <math.h>

typedef __bf16 bf16;
typedef __bf16 bf16x4 __attribute__((ext_vector_type(4)));
typedef __bf16 bf16x8 __attribute__((ext_vector_type(8)));
typedef float f32x2 __attribute__((ext_vector_type(2)));
typedef float f32x4 __attribute__((ext_vector_type(4)));

#define NB 4
#define NN 1024
#define ND 256
#define NH 8
#define INFV 1e38f
#define RTHR2 11.5f          // defer-max threshold, log2 domain (~e^8)
#define LOG2E 1.44269504f
#define ZSPLIT 4

__device__ __forceinline__ f32x4 mfma16(bf16x8 a, bf16x8 b, f32x4 c) {
    return __builtin_amdgcn_mfma_f32_16x16x32_bf16(a, b, c, 0, 0, 0);
}
__device__ __forceinline__ f32x2 sp2(float v) { return f32x2{v, v}; }
__device__ __forceinline__ f32x2 fma2(f32x2 a, float b, f32x2 c) {
    return __builtin_elementwise_fma(a, sp2(b), c);
}
// force a wave-uniform float into an SGPR
__device__ __forceinline__ float rfl(float x) {
    return __int_as_float(__builtin_amdgcn_readfirstlane(__float_as_int(x)));
}

// C = A(Mx256) @ W(256x64-tile) + bias. 64x64 tile, 4 waves (2x2), 256 thr.
// MODE0: A is f32; z<2 -> bf16 Go; z==2 -> bf16 Vfb + transposed bf16 Gt.
// MODE1: A and addsrc are bf16 (combined O1); Fo1 = addsrc + relu(C), f32 out.
template<int MODE>
__global__ __launch_bounds__(256)
void gemm_k(const float* __restrict__ A,
            const float* __restrict__ W0, const float* __restrict__ b0,
            const float* __restrict__ W1, const float* __restrict__ b1,
            const float* __restrict__ W2, const float* __restrict__ b2,
            bf16* __restrict__ Vfb, bf16* __restrict__ G0,
            bf16* __restrict__ G1, bf16* __restrict__ Gt,
            float* __restrict__ Fo1, const bf16* __restrict__ Ab)
{
    const int z = blockIdx.z;
    const float* W    = (z == 0) ? W0 : (z == 1) ? W1 : W2;
    const float* bias = (z == 0) ? b0 : (z == 1) ? b1 : b2;

    const int brow = blockIdx.x * 64;
    const int bcol = blockIdx.y * 64;
    const int t    = threadIdx.x;
    const int lane = t & 63;
    const int w    = t >> 6;
    const int wr   = w >> 1, wc = w & 1;
    const int g    = lane >> 4;
    const int l16  = lane & 15;

    __shared__ bf16 As[64][40];
    __shared__ bf16 Wt[64][40];

    f32x4 acc[2][2];
    #pragma unroll
    for (int i = 0; i < 2; ++i)
        #pragma unroll
        for (int j = 0; j < 2; ++j) acc[i][j] = f32x4{0.f, 0.f, 0.f, 0.f};

    const int ar = t >> 2, aj = (t & 3) * 8;
    const int wcid = t & 63, wk = (t >> 6) * 8;

    for (int k0 = 0; k0 < 256; k0 += 32) {
        if (MODE == 1) {
            // A already bf16 (combined O1) — direct 16B copy
            *(bf16x8*)&As[ar][aj] =
                *(const bf16x8*)&Ab[(size_t)(brow + ar)*ND + k0 + aj];
        } else {
            const float4 v0 = *(const float4*)&A[(size_t)(brow + ar)*ND + k0 + aj];
            const float4 v1 = *(const float4*)&A[(size_t)(brow + ar)*ND + k0 + aj + 4];
            bf16x8 w8 = { (bf16)v0.x, (bf16)v0.y, (bf16)v0.z, (bf16)v0.w,
                          (bf16)v1.x, (bf16)v1.y, (bf16)v1.z, (bf16)v1.w };
            *(bf16x8*)&As[ar][aj] = w8;
        }
        {
            bf16x8 w8;
            #pragma unroll
            for (int p = 0; p < 8; ++p)
                w8[p] = (bf16)W[(size_t)(k0 + wk + p)*ND + bcol + wcid];
            *(bf16x8*)&Wt[wcid][wk] = w8;
        }
        __syncthreads();

        bf16x8 af[2], bfj[2];
        #pragma unroll
        for (int i = 0; i < 2; ++i) af[i]  = *(const bf16x8*)&As[wr*32 + i*16 + l16][8*g];
        #pragma unroll
        for (int j = 0; j < 2; ++j) bfj[j] = *(const bf16x8*)&Wt[wc*32 + j*16 + l16][8*g];
        #pragma unroll
        for (int j = 0; j < 2; ++j)
            #pragma unroll
            for (int i = 0; i < 2; ++i) acc[i][j] = mfma16(af[i], bfj[j], acc[i][j]);
        __syncthreads();
    }

    #pragma unroll
    for (int j = 0; j < 2; ++j) {
        const int col = bcol + wc*32 + j*16 + l16;
        const float bj = bias[col];
        #pragma unroll
        for (int i = 0; i < 2; ++i) {
            const int row0 = brow + wr*32 + i*16 + 4*g;
            if (MODE == 1) {
                #pragma unroll
                for (int r = 0; r < 4; ++r) {
                    const size_t idx = (size_t)(row0 + r)*ND + col;
                    Fo1[idx] = (float)Ab[idx] + fmaxf(acc[i][j][r] + bj, 0.f);
                }
            } else if (z < 2) {
                bf16* Go = (z == 0) ? G0 : G1;
                #pragma unroll
                for (int r = 0; r < 4; ++r)
                    Go[(size_t)(row0 + r)*ND + col] = (bf16)(acc[i][j][r] + bj);
            } else {
                float vv[4];
                #pragma unroll
                for (int r = 0; r < 4; ++r) {
                    vv[r] = acc[i][j][r] + bj;
                    Vfb[(size_t)(row0 + r)*ND + col] = (bf16)vv[r];
                }
                const int b2 = row0 >> 10;
                const int n0 = row0 & 1023;
                bf16x4 tv = { (bf16)vv[0], (bf16)vv[1], (bf16)vv[2], (bf16)vv[3] };
                *(bf16x4*)&Gt[((size_t)b2*ND + col)*NN + n0] = tv;
            }
        }
    }
}

// Fused attention — R18/R20/R21 champion structure: 256 thr = 4 waves = 4
// heads (grid.y = batch*2); X_pairs staged cooperatively in LDS (dbuf, b128
// writes); K/V/X/pk register-prefetched one tile ahead; P transposed through
// wave-private LDS; gate weights in SGPRs; log2-domain defer-max softmax;
// ZSPLIT=4; bf16 Ohp partials. Best measured: 69.42us total.
__global__ __launch_bounds__(256, 4)
void attn_k(const bf16* __restrict__ Qb, const bf16* __restrict__ Kb,
            const bf16* __restrict__ Vt, const float* __restrict__ Xpg,
            const float* __restrict__ prq, const float* __restrict__ prk,
            const float* __restrict__ Wg1, const float* __restrict__ bg1,
            const float* __restrict__ wg2, const float* __restrict__ bg2,
            bf16* __restrict__ Ohp, float* __restrict__ ml)
{
    const int yb   = blockIdx.y;
    const int b    = yb >> 1;
    const int hg   = yb & 1;
    const int q0   = blockIdx.x * 16;
    const int z    = blockIdx.z;
    const int mb0  = z * (NN/ZSPLIT);
    const int t    = threadIdx.x;
    const int w    = t >> 6;        // wave 0..3
    const int h    = hg*4 + w;      // head 0..7
    const int lane = t & 63;
    const int g    = lane >> 4;
    const int l16  = lane & 15;
    const int NT   = NN/ZSPLIT/32;  // 8

    __shared__ float Xps[2][16*132];
    __shared__ bf16  Ps[4][16][40];

    // head gate weights -> SGPRs (wave-uniform); LOG2E folded into 2nd layer
    float g1[3][3], gb1[3], g2v[3], gb2v;
    #pragma unroll
    for (int c = 0; c < 3; ++c)
        #pragma unroll
        for (int d = 0; d < 3; ++d) g1[c][d] = rfl(Wg1[(h*3 + c)*3 + d]);
    #pragma unroll
    for (int d = 0; d < 3; ++d) {
        gb1[d] = rfl(bg1[h*3 + d]);
        g2v[d] = rfl(wg2[h*3 + d]*LOG2E);
    }
    gb2v = rfl(bg2[h]*LOG2E);
    const float sscale = 0.0625f * LOG2E;

    const bf16x8 qf = *(const bf16x8*)&Qb[((size_t)b*NN + q0 + l16)*ND + h*32 + 8*g];

    bool okq[4];
    #pragma unroll
    for (int r = 0; r < 4; ++r)
        okq[r] = prq[b*NN + q0 + 4*g + r] > 0.5f;

    float m_run[4], l_run[4];   // log2-domain max; per-lane partial sum
    f32x4 oh[2];
    #pragma unroll
    for (int r = 0; r < 4; ++r) { m_run[r] = -INFINITY; l_run[r] = 0.f; }
    oh[0] = f32x4{0.f,0.f,0.f,0.f};
    oh[1] = f32x4{0.f,0.f,0.f,0.f};

    const bf16*  kp0 = &Kb[((size_t)b*NN + mb0 + l16)*ND + h*32 + 8*g];
    const bf16*  kp1 = kp0 + (size_t)16*ND;
    const bf16*  vp0 = &Vt[((size_t)b*ND + h*32 + l16)*NN + mb0 + 8*g];
    const bf16*  vp1 = vp0 + (size_t)16*NN;
    const int    xq  = t >> 5, xm = t & 31;   // xq 0..7; stage rows xq and xq+8
    const float* xppA = &Xpg[(((size_t)b*NN + q0 + xq)*NN + mb0 + xm)*3];
    const float* xppB = &Xpg[(((size_t)b*NN + q0 + xq + 8)*NN + mb0 + xm)*3];
    const float* pkp  = &prk[(size_t)b*NN + mb0 + l16];

    // ---- prologue: tile-0 fragments + Xps[0] (b128 stores) ----
    bf16x8 kf0 = *(const bf16x8*)kp0;
    bf16x8 kf1 = *(const bf16x8*)kp1;
    bf16x8 vf0 = *(const bf16x8*)vp0;
    bf16x8 vf1 = *(const bf16x8*)vp1;
    float xxA = xppA[0], xyA = xppA[1], xzA = xppA[2];
    float xxB = xppB[0], xyB = xppB[1], xzB = xppB[2];
    float pk0 = pkp[0], pk1 = pkp[16];
    {
        *(float4*)&Xps[0][xq*132 + xm*4]       = float4{xxA, xyA, xzA, 0.f};
        *(float4*)&Xps[0][(xq + 8)*132 + xm*4] = float4{xxB, xyB, xzB, 0.f};
    }
    __syncthreads();

    for (int it = 0; it < NT; ++it) {
        const int cur = it & 1;

        // issue next-tile loads (consumed next iter)
        bf16x8 kn0, kn1, vn0, vn1;
        float  xnxA, xnyA, xnzA, xnxB, xnyB, xnzB, pn0, pn1;
        if (it + 1 < NT) {
            const int off = (it + 1) * 32;
            kn0 = *(const bf16x8*)(kp0 + (size_t)off*ND);
            kn1 = *(const bf16x8*)(kp1 + (size_t)off*ND);
            vn0 = *(const bf16x8*)(vp0 + off);
            vn1 = *(const bf16x8*)(vp1 + off);
            xnxA = xppA[(size_t)off*3];
            xnyA = xppA[(size_t)off*3 + 1];
            xnzA = xppA[(size_t)off*3 + 2];
            xnxB = xppB[(size_t)off*3];
            xnyB = xppB[(size_t)off*3 + 1];
            xnzB = xppB[(size_t)off*3 + 2];
            pn0 = pkp[off]; pn1 = pkp[off + 16];
        }

        // QK^T
        const f32x4 zero = {0.f,0.f,0.f,0.f};
        f32x4 s[2];
        s[0] = mfma16(qf, kf0, zero);
        s[1] = mfma16(qf, kf1, zero);

        const bool okk0 = pk0 > 0.5f;
        const bool okk1 = pk1 > 0.5f;

        // loc gate (packed f32 over r-pairs) + masks; log2 domain
        float lv[2][4];
        #pragma unroll
        for (int mg = 0; mg < 2; ++mg) {
            const bool okkm = mg ? okk1 : okk0;
            const int m = mg*16 + l16;
            #pragma unroll
            for (int rp = 0; rp < 2; ++rp) {
                const int q = 4*g + 2*rp;
                const float4 xa = *(const float4*)&Xps[cur][q*132 + m*4];
                const float4 xb = *(const float4*)&Xps[cur][(q+1)*132 + m*4];
                const f32x2 vx = {xa.x, xb.x};
                const f32x2 vy = {xa.y, xb.y};
                const f32x2 vz = {xa.z, xb.z};
                f32x2 h0 = fma2(vz, g1[2][0], fma2(vy, g1[1][0], fma2(vx, g1[0][0], sp2(gb1[0]))));
                f32x2 h1 = fma2(vz, g1[2][1], fma2(vy, g1[1][1], fma2(vx, g1[0][1], sp2(gb1[1]))));
                f32x2 h2 = fma2(vz, g1[2][2], fma2(vy, g1[1][2], fma2(vx, g1[0][2], sp2(gb1[2]))));
                const f32x2 zz = {0.f, 0.f};
                h0 = __builtin_elementwise_max(h0, zz);
                h1 = __builtin_elementwise_max(h1, zz);
                h2 = __builtin_elementwise_max(h2, zz);
                f32x2 loc = fma2(h2, g2v[2], fma2(h1, g2v[1], fma2(h0, g2v[0], sp2(gb2v))));
                const f32x2 s2 = { s[mg][2*rp], s[mg][2*rp+1] };
                const f32x2 y = fma2(s2, sscale, loc);
                lv[mg][2*rp]   = (okq[2*rp]   && okkm) ? y.x : -INFV;
                lv[mg][2*rp+1] = (okq[2*rp+1] && okkm) ? y.y : -INFV;
            }
        }

        // defer-max online softmax (log2 domain)
        float pm[4];
        #pragma unroll
        for (int r = 0; r < 4; ++r) pm[r] = fmaxf(lv[0][r], lv[1][r]);
        const bool cond = (pm[0] <= m_run[0] + RTHR2) && (pm[1] <= m_run[1] + RTHR2)
                       && (pm[2] <= m_run[2] + RTHR2) && (pm[3] <= m_run[3] + RTHR2);
        if (!__all((int)cond)) {
            #pragma unroll
            for (int r = 0; r < 4; ++r) {
                float mx = pm[r];
                mx = fmaxf(mx, __shfl_xor(mx, 1));
                mx = fmaxf(mx, __shfl_xor(mx, 2));
                mx = fmaxf(mx, __shfl_xor(mx, 4));
                mx = fmaxf(mx, __shfl_xor(mx, 8));
                const float mnew = fmaxf(m_run[r], mx);
                const float corr = exp2f(m_run[r] - mnew);
                l_run[r] *= corr;
                oh[0][r] *= corr;
                oh[1][r] *= corr;
                m_run[r] = mnew;
            }
        }
        #pragma unroll
        for (int r = 0; r < 4; ++r) {
            const float p0 = exp2f(lv[0][r] - m_run[r]);
            const float p1 = exp2f(lv[1][r] - m_run[r]);
            Ps[w][4*g + r][l16]      = (bf16)p0;
            Ps[w][4*g + r][16 + l16] = (bf16)p1;
            l_run[r] += p0 + p1;
        }

        // PV (compiler orders Ps write->read with a precise lgkmcnt)
        const bf16x8 pf = *(const bf16x8*)&Ps[w][l16][8*g];
        oh[0] = mfma16(pf, vf0, oh[0]);
        oh[1] = mfma16(pf, vf1, oh[1]);

        // stage next X tile into the other buffer (b128); rotate registers
        if (it + 1 < NT) {
            *(float4*)&Xps[cur ^ 1][xq*132 + xm*4]       = float4{xnxA, xnyA, xnzA, 0.f};
            *(float4*)&Xps[cur ^ 1][(xq + 8)*132 + xm*4] = float4{xnxB, xnyB, xnzB, 0.f};
            kf0 = kn0; kf1 = kn1; vf0 = vn0; vf1 = vn1;
            pk0 = pn0; pk1 = pn1;
        }
        __syncthreads();
    }

    // epilogue: unnormalized partial oh (bf16) + (m, l) per row/head
    #pragma unroll
    for (int r = 0; r < 4; ++r) {
        float ls = l_run[r];
        ls += __shfl_xor(ls, 1);
        ls += __shfl_xor(ls, 2);
        ls += __shfl_xor(ls, 4);
        ls += __shfl_xor(ls, 8);
        const int n = q0 + 4*g + r;
        #pragma unroll
        for (int dg = 0; dg < 2; ++dg) {
            const int col = h*32 + dg*16 + l16;
            Ohp[(((size_t)z*NB + b)*NN + n)*ND + col] = (bf16)oh[dg][r];
        }
        if (l16 == 0) {
            const size_t mi = ((((size_t)z*NB + b)*NN + n)*NH + h)*2;
            ml[mi]   = m_run[r];
            ml[mi+1] = ls;
        }
    }
}

// combine ZSPLIT key-quarters: O1 = Vf + (Σ oh_z w_z) / (Σ l_z w_z), bf16 out
__global__ __launch_bounds__(256)
void comb_k(const bf16* __restrict__ Ohp, const float* __restrict__ ml,
            const bf16* __restrict__ Vfb, bf16* __restrict__ O1b)
{
    const int idx = blockIdx.x * 256 + threadIdx.x;
    const int dq = idx & 63;
    const int bn = idx >> 6;
    const int d0 = dq * 4;
    const int h  = dq >> 3;

    const size_t base = ((size_t)bn*NH + h)*2;
    const size_t zstr = (size_t)NB*NN*NH*2;
    float mz[ZSPLIT], lz[ZSPLIT];
    float M = -INFINITY;
    #pragma unroll
    for (int zi = 0; zi < ZSPLIT; ++zi) {
        mz[zi] = ml[base + zi*zstr];
        lz[zi] = ml[base + zi*zstr + 1];
        M = fmaxf(M, mz[zi]);
    }
    float wz[ZSPLIT], den = 0.f;
    #pragma unroll
    for (int zi = 0; zi < ZSPLIT; ++zi) {
        wz[zi] = exp2f(mz[zi] - M);
        den = fmaf(lz[zi], wz[zi], den);
    }
    const float inv = 1.f / den;

    const size_t e = (size_t)bn*ND + d0;
    f32x4 num = {0.f,0.f,0.f,0.f};
    #pragma unroll
    for (int zi = 0; zi < ZSPLIT; ++zi) {
        const bf16x4 o = *(const bf16x4*)&Ohp[e + (size_t)zi*NB*NN*ND];
        #pragma unroll
        for (int r = 0; r < 4; ++r) num[r] = fmaf((float)o[r], wz[zi], num[r]);
    }
    const bf16x4 vf = *(const bf16x4*)&Vfb[e];
    bf16x4 out;
    #pragma unroll
    for (int r = 0; r < 4; ++r) out[r] = (bf16)((float)vf[r] + num[r]*inv);
    *(bf16x4*)&O1b[e] = out;
}

extern "C" void kernel_launch(void* const* d_in, const int* in_sizes, int n_in,
                              void* d_out, int out_size, void* d_ws, size_t ws_size,
                              hipStream_t stream)
{
    const float* Y   = (const float*)d_in[1];
    const float* Xp  = (const float*)d_in[2];
    const float* prq = (const float*)d_in[3];
    const float* prk = (const float*)d_in[4];
    const float* Wq  = (const float*)d_in[5];
    const float* bq  = (const float*)d_in[6];
    const float* Wk  = (const float*)d_in[7];
    const float* bk  = (const float*)d_in[8];
    const float* Wv  = (const float*)d_in[9];
    const float* bv  = (const float*)d_in[10];
    const float* Wo  = (const float*)d_in[11];
    const float* bo  = (const float*)d_in[12];
    const float* Wg1 = (const float*)d_in[13];
    const float* bg1 = (const float*)d_in[14];
    const float* wg2 = (const float*)d_in[15];
    const float* bg2 = (const float*)d_in[16];
    float* out = (float*)d_out;

    const size_t BND = (size_t)NB * NN * ND;   // 1M
    bf16*  Vfb = (bf16*)d_ws;                            // 2 MB
    bf16*  Ohp = Vfb + BND;                              // 8 MB (z=0..3, bf16)
    float* ml  = (float*)(Ohp + (size_t)ZSPLIT*BND);     // 1 MB
    bf16*  Qb  = (bf16*)(ml + (size_t)ZSPLIT*NB*NN*NH*2);// 2 MB
    bf16*  Kb  = Qb + BND;                               // 2 MB
    bf16*  Vt  = Kb + BND;                               // 2 MB
    bf16*  O1b = Qb;                                     // aliases Qb (dead after attn)

    gemm_k<0><<<dim3(64, 4, 3), 256, 0, stream>>>(
        Y, Wq, bq, Wk, bk, Wv, bv,
        Vfb, Qb, Kb, Vt, nullptr, nullptr);

    attn_k<<<dim3(NN/16, NB*2, ZSPLIT), 256, 0, stream>>>(
        Qb, Kb, Vt, Xp, prq, prk, Wg1, bg1, wg2, bg2, Ohp, ml);

    comb_k<<<dim3(1024), 256, 0, stream>>>(Ohp, ml, Vfb, O1b);

    gemm_k<1><<<dim3(64, 4, 1), 256, 0, stream>>>(
        nullptr, Wo, bo, Wo, bo, Wo, bo,
        nullptr, nullptr, nullptr, nullptr, out, O1b);
}